// Round 11
// baseline (369.307 us; speedup 1.0000x reference)
//
#include <hip/hip_runtime.h>

typedef unsigned short u16;
typedef unsigned int u32;
typedef __attribute__((ext_vector_type(8))) unsigned short u16x8;
typedef __attribute__((ext_vector_type(4))) unsigned int u32x4;

constexpr int IN_F = 128;
constexpr int HID  = 256;
constexpr int OUT_F = 64;

static inline int cdiv_i(long long a, long long b) { return (int)((a + b - 1) / b); }

__device__ inline float b2f(u16 h) { return __uint_as_float(((u32)h) << 16); }
__device__ inline u16 f2b(float f) {
    u32 u = __float_as_uint(f);
    u32 r = (u + 0x7FFFu + ((u >> 16) & 1u)) >> 16;   // RNE
    return (u16)r;
}
__device__ inline float4 ld4(const float* p) { return *reinterpret_cast<const float4*>(p); }

// ================= CSR build =================
__global__ __launch_bounds__(256) void deg_count_kernel(
    const int* __restrict__ ei, int* __restrict__ deg, int E)
{
    int e = blockIdx.x * blockDim.x + threadIdx.x;
    if (e >= E) return;
    atomicAdd(&deg[ei[E + e]], 1);
}

__global__ __launch_bounds__(1024) void block_scan_kernel(
    const int* __restrict__ deg, int* __restrict__ row_ptr,
    int* __restrict__ blksum, int Nn)
{
    __shared__ int buf[1024];
    int i = blockIdx.x * 1024 + threadIdx.x;
    int v = (i < Nn) ? deg[i] : 0;
    buf[threadIdx.x] = v;
    __syncthreads();
    for (int off = 1; off < 1024; off <<= 1) {
        int t = (threadIdx.x >= off) ? buf[threadIdx.x - off] : 0;
        __syncthreads();
        buf[threadIdx.x] += t;
        __syncthreads();
    }
    if (i < Nn) row_ptr[i] = buf[threadIdx.x] - v;   // local exclusive
    if (threadIdx.x == 1023) blksum[blockIdx.x] = buf[1023];
}

__global__ __launch_bounds__(1024) void scan_blksums_kernel(
    int* __restrict__ blksum, int nblk)
{
    __shared__ int buf[1024];
    int v = (threadIdx.x < nblk) ? blksum[threadIdx.x] : 0;
    buf[threadIdx.x] = v;
    __syncthreads();
    for (int off = 1; off < 1024; off <<= 1) {
        int t = (threadIdx.x >= off) ? buf[threadIdx.x - off] : 0;
        __syncthreads();
        buf[threadIdx.x] += t;
        __syncthreads();
    }
    if (threadIdx.x < nblk) blksum[threadIdx.x] = buf[threadIdx.x] - v;  // exclusive
}

__global__ __launch_bounds__(1024) void add_offsets_kernel(
    int* __restrict__ row_ptr, int* __restrict__ cursor,
    const int* __restrict__ blksum, int Nn, int E)
{
    int i = blockIdx.x * 1024 + threadIdx.x;
    if (i < Nn) {
        int r = row_ptr[i] + blksum[i >> 10];
        row_ptr[i] = r;
        cursor[i]  = r;
    } else if (i == Nn) {
        row_ptr[Nn] = E;
    }
}

__global__ __launch_bounds__(256) void csr_fill_kernel(
    const int* __restrict__ ei, int* __restrict__ cursor,
    int* __restrict__ csr_src, int E)
{
    int e = blockIdx.x * blockDim.x + threadIdx.x;
    if (e >= E) return;
    int d = ei[E + e];
    int pos = atomicAdd(&cursor[d], 1);
    csr_src[pos] = ei[e];
}

// ================= conversions =================
__global__ __launch_bounds__(256) void xconv_kernel(
    const float4* __restrict__ in, ushort4* __restrict__ out, long long total4)
{
    long long i = (long long)blockIdx.x * blockDim.x + threadIdx.x;
    if (i >= total4) return;
    float4 v = in[i];
    ushort4 o;
    o.x = f2b(v.x); o.y = f2b(v.y); o.z = f2b(v.z); o.w = f2b(v.w);
    out[i] = o;
}

// All six weights fp32 [K][NC] -> bf16 [NC][K], one launch.
__global__ __launch_bounds__(256) void wconv_all_kernel(
    const float* __restrict__ W01, const float* __restrict__ W02,
    const float* __restrict__ W11, const float* __restrict__ W12,
    const float* __restrict__ W21, const float* __restrict__ W22,
    u16* __restrict__ Wt01, u16* __restrict__ Wt02,
    u16* __restrict__ Wt11, u16* __restrict__ Wt12,
    u16* __restrict__ Wt21, u16* __restrict__ Wt22)
{
    int id = blockIdx.x * blockDim.x + threadIdx.x;
    const float* W; u16* Wt; int kshift, NC;
    if (id < 32768)                  { W = W01; Wt = Wt01; kshift = 7; NC = 256; }
    else if ((id -= 32768) < 65536)  { W = W02; Wt = Wt02; kshift = 8; NC = 256; }
    else if ((id -= 65536) < 65536)  { W = W11; Wt = Wt11; kshift = 8; NC = 256; }
    else if ((id -= 65536) < 65536)  { W = W12; Wt = Wt12; kshift = 8; NC = 256; }
    else if ((id -= 65536) < 65536)  { W = W21; Wt = Wt21; kshift = 8; NC = 256; }
    else if ((id -= 65536) < 16384)  { W = W22; Wt = Wt22; kshift = 8; NC = 64;  }
    else return;
    int K = 1 << kshift;
    int n = id >> kshift;
    int k = id & (K - 1);
    Wt[id] = f2b(W[(long long)k * NC + n]);
}

// ================= gather aggregation (bf16, fp32 accum) =================
// Lane owns 16B (8 bf16); 2 edge-groups of 32 lanes; unroll-4 gathers in
// flight per group (latency-bound: maximize outstanding loads).
__global__ __launch_bounds__(256) void agg256_bf16(
    const u16x8* __restrict__ x, const int* __restrict__ row_ptr,
    const int* __restrict__ csr_src, const float* __restrict__ eps_ptr,
    u16x8* __restrict__ out, int Nn)
{
    int n = blockIdx.x * 4 + (threadIdx.x >> 6);
    if (n >= Nn) return;
    int lane = threadIdx.x & 63;
    int grp = lane >> 5;       // 0/1
    int sl  = lane & 31;       // chunk index
    size_t off = (size_t)n * 32 + sl;
    float acc[8];
    if (grp == 0) {
        float e1 = 1.0f + (eps_ptr ? *eps_ptr : 0.0f);
        u16x8 xv = x[off];
#pragma unroll
        for (int i = 0; i < 8; ++i) acc[i] = e1 * b2f(xv[i]);
    } else {
#pragma unroll
        for (int i = 0; i < 8; ++i) acc[i] = 0.0f;
    }
    int end = row_ptr[n + 1];
    int j = row_ptr[n] + grp;
    for (; j + 6 < end; j += 8) {          // 4 edges/group in flight
        int s0 = csr_src[j],     s1 = csr_src[j + 2];
        int s2 = csr_src[j + 4], s3 = csr_src[j + 6];
        u16x8 v0 = x[(size_t)s0 * 32 + sl];
        u16x8 v1 = x[(size_t)s1 * 32 + sl];
        u16x8 v2 = x[(size_t)s2 * 32 + sl];
        u16x8 v3 = x[(size_t)s3 * 32 + sl];
#pragma unroll
        for (int i = 0; i < 8; ++i)
            acc[i] += (b2f(v0[i]) + b2f(v1[i])) + (b2f(v2[i]) + b2f(v3[i]));
    }
    for (; j < end; j += 2) {
        u16x8 v = x[(size_t)csr_src[j] * 32 + sl];
#pragma unroll
        for (int i = 0; i < 8; ++i) acc[i] += b2f(v[i]);
    }
#pragma unroll
    for (int i = 0; i < 8; ++i) acc[i] += __shfl_xor(acc[i], 32, 64);
    if (grp == 0) {
        u16x8 o;
#pragma unroll
        for (int i = 0; i < 8; ++i) o[i] = f2b(acc[i]);
        out[off] = o;
    }
}

__global__ __launch_bounds__(256) void agg128_bf16(
    const u16x8* __restrict__ x, const int* __restrict__ row_ptr,
    const int* __restrict__ csr_src, const float* __restrict__ eps_ptr,
    u16x8* __restrict__ out, int Nn)
{
    int n = blockIdx.x * 4 + (threadIdx.x >> 6);
    if (n >= Nn) return;
    int lane = threadIdx.x & 63;
    int grp = lane >> 4;       // 0..3
    int sl  = lane & 15;
    size_t off = (size_t)n * 16 + sl;
    float acc[8];
    if (grp == 0) {
        float e1 = 1.0f + (eps_ptr ? *eps_ptr : 0.0f);
        u16x8 xv = x[off];
#pragma unroll
        for (int i = 0; i < 8; ++i) acc[i] = e1 * b2f(xv[i]);
    } else {
#pragma unroll
        for (int i = 0; i < 8; ++i) acc[i] = 0.0f;
    }
    int end = row_ptr[n + 1];
    int j = row_ptr[n] + grp;
    for (; j + 4 < end; j += 8) {
        int s0 = csr_src[j], s1 = csr_src[j + 4];
        u16x8 v0 = x[(size_t)s0 * 16 + sl];
        u16x8 v1 = x[(size_t)s1 * 16 + sl];
#pragma unroll
        for (int i = 0; i < 8; ++i) acc[i] += b2f(v0[i]) + b2f(v1[i]);
    }
    if (j < end) {
        u16x8 v = x[(size_t)csr_src[j] * 16 + sl];
#pragma unroll
        for (int i = 0; i < 8; ++i) acc[i] += b2f(v[i]);
    }
#pragma unroll
    for (int i = 0; i < 8; ++i) {
        acc[i] += __shfl_xor(acc[i], 16, 64);
        acc[i] += __shfl_xor(acc[i], 32, 64);
    }
    if (grp == 0) {
        u16x8 o;
#pragma unroll
        for (int i = 0; i < 8; ++i) o[i] = f2b(acc[i]);
        out[off] = o;
    }
}

// ================= weight-in-registers persistent GEMM =================
// C[M,NC] = A[M,K](bf16) @ Wt[NC,K](bf16)^T (+bias; FUSE 0=ReLU,1=BN+LReLU,2=none)
// 512 thr / 8 waves, 2 blocks/CU (launch_bounds caps VGPR<=128).
// Each wave holds ITS W-slice in REGISTERS (wreg[K/32][NF], statically
// indexed -> stays in VGPRs), loaded once per block from L2/L3-resident Wt.
// Grid-stride over 32-row A-tiles: reg-prefetch A(t+1) under compute (T14),
// ds_write -> barrier -> K/32 pure-LDS+reg k-steps -> epilogue -> barrier.
// LDS = A tile only (16KB @K=256). Per k-step: 2 A ds_reads + MF*NF MFMAs.
// Swapped-operand MFMA: D=mfma(W,A): W-row(out col) -> (l>>4)*4+j, node -> l&15.
// A LDS layout: logical granule g of row r at physical g^(r&7).
using bf16x8 = __attribute__((ext_vector_type(8))) short;
using f32x4  = __attribute__((ext_vector_type(4))) float;

template <int K, int NC, int FUSE, bool OF32>
__global__ __launch_bounds__(512, 4) void gemm_wreg(
    const u16* __restrict__ A, const u16* __restrict__ Wt,
    const float* __restrict__ bias,
    const float* __restrict__ bn_g, const float* __restrict__ bn_b,
    const float* __restrict__ bn_m, const float* __restrict__ bn_v,
    void* __restrict__ Cout, int M, int ntiles)
{
    constexpr int GPR  = K / 8;                    // 16B granules per row
    constexpr int AREG = (32 * GPR) / 512;         // granules per thread (1 or 2)
    constexpr int KS   = K / 32;                   // k-steps
    constexpr int MF   = (NC == 256) ? 2 : 1;
    constexpr int NF   = (NC == 256) ? 2 : 1;
    __shared__ __align__(16) u16 Al[32 * K];

    const int tid  = threadIdx.x;
    const int wv   = tid >> 6;
    const int lane = tid & 63;
    const int l15  = lane & 15, l4 = lane >> 4;
    const int rbase = (NC == 256) ? 0 : (wv >> 2) * 16;
    const int cbase = (NC == 256) ? wv * 32 : (wv & 3) * 16;

    // ---- load this wave's W slice into registers (once) ----
    bf16x8 wreg[KS][NF];
#pragma unroll
    for (int s = 0; s < KS; ++s)
#pragma unroll
        for (int n = 0; n < NF; ++n) {
            int wrow = cbase + n * 16 + l15;
            wreg[s][n] = *(const bf16x8*)(Wt + (size_t)wrow * K + (s * 4 + l4) * 8);
        }

    // ---- per-thread A-tile register prefetch ----
    u32x4 areg[AREG];
    auto loadA = [&](int t) {
#pragma unroll
        for (int i = 0; i < AREG; ++i) {
            int gi = i * 512 + tid;
            int row = gi / GPR;
            int g = gi % GPR;
            int grow = t * 32 + row; if (grow >= M) grow = M - 1;
            areg[i] = *reinterpret_cast<const u32x4*>(
                A + (size_t)grow * K + (g ^ (row & 7)) * 8);
        }
    };

    loadA(blockIdx.x);

    for (int t = blockIdx.x; t < ntiles; t += gridDim.x) {
        // write A(t) regs -> LDS (linear granules; content pre-swizzled)
#pragma unroll
        for (int i = 0; i < AREG; ++i) {
            int gi = i * 512 + tid;
            *reinterpret_cast<u32x4*>(Al + gi * 8) = areg[i];
        }
        __syncthreads();                   // A visible

        int tn = t + gridDim.x;
        if (tn < ntiles) loadA(tn);        // in flight under compute

        f32x4 acc[MF][NF] = {};
#pragma unroll
        for (int s = 0; s < KS; ++s) {
            int g = s * 4 + l4;
            bf16x8 af[MF];
#pragma unroll
            for (int m = 0; m < MF; ++m) {
                int arow = rbase + m * 16 + l15;
                af[m] = *(const bf16x8*)(Al + arow * K + ((g ^ (arow & 7)) * 8));
            }
#pragma unroll
            for (int m = 0; m < MF; ++m)
#pragma unroll
                for (int n = 0; n < NF; ++n)
                    acc[m][n] = __builtin_amdgcn_mfma_f32_16x16x32_bf16(
                        wreg[s][n], af[m], acc[m][n], 0, 0, 0);
        }

        // ---- fused epilogue, store tile t ----
#pragma unroll
        for (int m = 0; m < MF; ++m) {
            int grow = t * 32 + rbase + m * 16 + l15;
            if (grow < M) {
#pragma unroll
                for (int n = 0; n < NF; ++n) {
                    int col = cbase + n * 16 + l4 * 4;
                    float4 bv = ld4(bias + col);
                    float v0 = acc[m][n][0] + bv.x;
                    float v1 = acc[m][n][1] + bv.y;
                    float v2 = acc[m][n][2] + bv.z;
                    float v3 = acc[m][n][3] + bv.w;
                    if (FUSE == 0) {
                        v0 = fmaxf(v0, 0.f); v1 = fmaxf(v1, 0.f);
                        v2 = fmaxf(v2, 0.f); v3 = fmaxf(v3, 0.f);
                    } else if (FUSE == 1) {
                        float4 g4 = ld4(bn_g + col), be = ld4(bn_b + col);
                        float4 mm = ld4(bn_m + col), vv = ld4(bn_v + col);
                        float s0 = g4.x * rsqrtf(vv.x + 1e-5f);
                        float s1 = g4.y * rsqrtf(vv.y + 1e-5f);
                        float s2 = g4.z * rsqrtf(vv.z + 1e-5f);
                        float s3 = g4.w * rsqrtf(vv.w + 1e-5f);
                        v0 = fmaf(v0, s0, be.x - mm.x * s0);
                        v1 = fmaf(v1, s1, be.y - mm.y * s1);
                        v2 = fmaf(v2, s2, be.z - mm.z * s2);
                        v3 = fmaf(v3, s3, be.w - mm.w * s3);
                        v0 = v0 >= 0.f ? v0 : 0.01f * v0;
                        v1 = v1 >= 0.f ? v1 : 0.01f * v1;
                        v2 = v2 >= 0.f ? v2 : 0.01f * v2;
                        v3 = v3 >= 0.f ? v3 : 0.01f * v3;
                    }
                    if (OF32) {
                        float4 o = make_float4(v0, v1, v2, v3);
                        *reinterpret_cast<float4*>(
                            (float*)Cout + (size_t)grow * NC + col) = o;
                    } else {
                        u32 p0 = (u32)f2b(v0) | ((u32)f2b(v1) << 16);
                        u32 p1 = (u32)f2b(v2) | ((u32)f2b(v3) << 16);
                        *reinterpret_cast<uint2*>(
                            (u16*)Cout + (size_t)grow * NC + col) = make_uint2(p0, p1);
                    }
                }
            }
        }
        __syncthreads();   // all waves done reading Al before next overwrite
    }
}

extern "C" void kernel_launch(void* const* d_in, const int* in_sizes, int n_in,
                              void* d_out, int out_size, void* d_ws, size_t ws_size,
                              hipStream_t stream)
{
    const float* x    = (const float*)d_in[0];
    const int*   ei   = (const int*)d_in[1];     // int32: [src(E), dst(E)]
    const float* eps0 = (const float*)d_in[2];
    const float* W01  = (const float*)d_in[3];
    const float* b01  = (const float*)d_in[4];
    const float* W02  = (const float*)d_in[5];
    const float* b02  = (const float*)d_in[6];
    const float* W11  = (const float*)d_in[7];
    const float* b11  = (const float*)d_in[8];
    const float* W12  = (const float*)d_in[9];
    const float* b12  = (const float*)d_in[10];
    const float* eps2 = (const float*)d_in[11];
    const float* W21  = (const float*)d_in[12];
    const float* b21  = (const float*)d_in[13];
    const float* W22  = (const float*)d_in[14];
    const float* b22  = (const float*)d_in[15];
    const float* bn_g = (const float*)d_in[16];
    const float* bn_b = (const float*)d_in[17];
    const float* bn_m = (const float*)d_in[18];
    const float* bn_v = (const float*)d_in[19];

    const int Nn = in_sizes[0] / IN_F;   // 50000
    const int E  = in_sizes[1] / 2;      // 600000

    // ---- workspace carve-up ----
    u16* P = (u16*)d_ws;                        // agg output
    u16* Q = P + (size_t)Nn * HID;              // layer output
    u16* R = Q + (size_t)Nn * HID;              // H intermediate
    u16* Xb = R + (size_t)Nn * HID;
    u16* Wt01 = Xb + (size_t)Nn * IN_F;
    u16* Wt02 = Wt01 + HID * IN_F;
    u16* Wt11 = Wt02 + HID * HID;
    u16* Wt12 = Wt11 + HID * HID;
    u16* Wt21 = Wt12 + HID * HID;
    u16* Wt22 = Wt21 + HID * HID;
    int* row_ptr = (int*)(Wt22 + OUT_F * HID);
    int* cursor  = row_ptr + (Nn + 1);
    int* deg     = cursor + Nn;
    int* blksum  = deg + Nn;
    int* csr_src = blksum + 1024;

    dim3 blk(256);
    const int nwave_blocks = cdiv_i(Nn, 4);
    const int nscan = cdiv_i(Nn, 1024);

    // ---- CSR build (by dst), two-level scan ----
    hipMemsetAsync(deg, 0, (size_t)Nn * sizeof(int), stream);
    deg_count_kernel<<<cdiv_i(E, 256), blk, 0, stream>>>(ei, deg, E);
    block_scan_kernel<<<nscan, 1024, 0, stream>>>(deg, row_ptr, blksum, Nn);
    scan_blksums_kernel<<<1, 1024, 0, stream>>>(blksum, nscan);
    add_offsets_kernel<<<cdiv_i(Nn + 1, 1024), 1024, 0, stream>>>(
        row_ptr, cursor, blksum, Nn, E);
    csr_fill_kernel<<<cdiv_i(E, 256), blk, 0, stream>>>(ei, cursor, csr_src, E);

    // ---- convert x and weights to bf16 ----
    xconv_kernel<<<cdiv_i((long long)Nn * IN_F / 4, 256), blk, 0, stream>>>(
        (const float4*)x, (ushort4*)Xb, (long long)Nn * IN_F / 4);
    wconv_all_kernel<<<cdiv_i(32768 + 4 * 65536 + 16384, 256), blk, 0, stream>>>(
        W01, W02, W11, W12, W21, W22, Wt01, Wt02, Wt11, Wt12, Wt21, Wt22);

    const int ntiles = cdiv_i(Nn, 32);          // 1563
    const dim3 blk512(512);
    const int ggrid = 512;                      // 2 blocks/CU

    // ================= layer 0 (in=128) =================
    agg128_bf16<<<nwave_blocks, blk, 0, stream>>>(
        (const u16x8*)Xb, row_ptr, csr_src, eps0, (u16x8*)P, Nn);
    gemm_wreg<128, 256, 0, false><<<ggrid, blk512, 0, stream>>>(
        P, Wt01, b01, nullptr, nullptr, nullptr, nullptr, R, Nn, ntiles);
    gemm_wreg<256, 256, 1, false><<<ggrid, blk512, 0, stream>>>(
        R, Wt02, b02, bn_g, bn_b, bn_m, bn_v, Q, Nn, ntiles);

    // ================= layer 1 =================
    agg256_bf16<<<nwave_blocks, blk, 0, stream>>>(
        (const u16x8*)Q, row_ptr, csr_src, nullptr, (u16x8*)P, Nn);
    gemm_wreg<256, 256, 0, false><<<ggrid, blk512, 0, stream>>>(
        P, Wt11, b11, nullptr, nullptr, nullptr, nullptr, R, Nn, ntiles);
    gemm_wreg<256, 256, 1, false><<<ggrid, blk512, 0, stream>>>(
        R, Wt12, b12, bn_g, bn_b, bn_m, bn_v, Q, Nn, ntiles);

    // ================= layer 2 (out=64) =================
    agg256_bf16<<<nwave_blocks, blk, 0, stream>>>(
        (const u16x8*)Q, row_ptr, csr_src, eps2, (u16x8*)P, Nn);
    gemm_wreg<256, 256, 0, false><<<ggrid, blk512, 0, stream>>>(
        P, Wt21, b21, nullptr, nullptr, nullptr, nullptr, R, Nn, ntiles);
    gemm_wreg<256, 64, 2, true><<<ggrid, blk512, 0, stream>>>(
        R, Wt22, b22, nullptr, nullptr, nullptr, nullptr, d_out, Nn, ntiles);
}

// Round 12
// 322.633 us; speedup vs baseline: 1.1447x; 1.1447x over previous
//
#include <hip/hip_runtime.h>

typedef unsigned short u16;
typedef unsigned int u32;
typedef __attribute__((ext_vector_type(8))) unsigned short u16x8;
typedef __attribute__((ext_vector_type(4))) unsigned int u32x4;

constexpr int IN_F = 128;
constexpr int HID  = 256;
constexpr int OUT_F = 64;

static inline int cdiv_i(long long a, long long b) { return (int)((a + b - 1) / b); }

__device__ inline float b2f(u16 h) { return __uint_as_float(((u32)h) << 16); }
__device__ inline u16 f2b(float f) {
    u32 u = __float_as_uint(f);
    u32 r = (u + 0x7FFFu + ((u >> 16) & 1u)) >> 16;   // RNE
    return (u16)r;
}
__device__ inline float4 ld4(const float* p) { return *reinterpret_cast<const float4*>(p); }

// ================= CSR build =================
__global__ __launch_bounds__(256) void deg_count_kernel(
    const int* __restrict__ ei, int* __restrict__ deg, int E)
{
    int e = blockIdx.x * blockDim.x + threadIdx.x;
    if (e >= E) return;
    atomicAdd(&deg[ei[E + e]], 1);
}

__global__ __launch_bounds__(1024) void block_scan_kernel(
    const int* __restrict__ deg, int* __restrict__ row_ptr,
    int* __restrict__ blksum, int Nn)
{
    __shared__ int buf[1024];
    int i = blockIdx.x * 1024 + threadIdx.x;
    int v = (i < Nn) ? deg[i] : 0;
    buf[threadIdx.x] = v;
    __syncthreads();
    for (int off = 1; off < 1024; off <<= 1) {
        int t = (threadIdx.x >= off) ? buf[threadIdx.x - off] : 0;
        __syncthreads();
        buf[threadIdx.x] += t;
        __syncthreads();
    }
    if (i < Nn) row_ptr[i] = buf[threadIdx.x] - v;   // local exclusive
    if (threadIdx.x == 1023) blksum[blockIdx.x] = buf[1023];
}

__global__ __launch_bounds__(1024) void scan_blksums_kernel(
    int* __restrict__ blksum, int nblk)
{
    __shared__ int buf[1024];
    int v = (threadIdx.x < nblk) ? blksum[threadIdx.x] : 0;
    buf[threadIdx.x] = v;
    __syncthreads();
    for (int off = 1; off < 1024; off <<= 1) {
        int t = (threadIdx.x >= off) ? buf[threadIdx.x - off] : 0;
        __syncthreads();
        buf[threadIdx.x] += t;
        __syncthreads();
    }
    if (threadIdx.x < nblk) blksum[threadIdx.x] = buf[threadIdx.x] - v;  // exclusive
}

__global__ __launch_bounds__(1024) void add_offsets_kernel(
    int* __restrict__ row_ptr, int* __restrict__ cursor,
    const int* __restrict__ blksum, int Nn, int E)
{
    int i = blockIdx.x * 1024 + threadIdx.x;
    if (i < Nn) {
        int r = row_ptr[i] + blksum[i >> 10];
        row_ptr[i] = r;
        cursor[i]  = r;
    } else if (i == Nn) {
        row_ptr[Nn] = E;
    }
}

__global__ __launch_bounds__(256) void csr_fill_kernel(
    const int* __restrict__ ei, int* __restrict__ cursor,
    int* __restrict__ csr_src, int E)
{
    int e = blockIdx.x * blockDim.x + threadIdx.x;
    if (e >= E) return;
    int d = ei[E + e];
    int pos = atomicAdd(&cursor[d], 1);
    csr_src[pos] = ei[e];
}

// ================= conversions =================
__global__ __launch_bounds__(256) void xconv_kernel(
    const float4* __restrict__ in, ushort4* __restrict__ out, long long total4)
{
    long long i = (long long)blockIdx.x * blockDim.x + threadIdx.x;
    if (i >= total4) return;
    float4 v = in[i];
    ushort4 o;
    o.x = f2b(v.x); o.y = f2b(v.y); o.z = f2b(v.z); o.w = f2b(v.w);
    out[i] = o;
}

// All six weights fp32 [K][NC] -> bf16 [NC][K], one launch.
__global__ __launch_bounds__(256) void wconv_all_kernel(
    const float* __restrict__ W01, const float* __restrict__ W02,
    const float* __restrict__ W11, const float* __restrict__ W12,
    const float* __restrict__ W21, const float* __restrict__ W22,
    u16* __restrict__ Wt01, u16* __restrict__ Wt02,
    u16* __restrict__ Wt11, u16* __restrict__ Wt12,
    u16* __restrict__ Wt21, u16* __restrict__ Wt22)
{
    int id = blockIdx.x * blockDim.x + threadIdx.x;
    const float* W; u16* Wt; int kshift, NC;
    if (id < 32768)                  { W = W01; Wt = Wt01; kshift = 7; NC = 256; }
    else if ((id -= 32768) < 65536)  { W = W02; Wt = Wt02; kshift = 8; NC = 256; }
    else if ((id -= 65536) < 65536)  { W = W11; Wt = Wt11; kshift = 8; NC = 256; }
    else if ((id -= 65536) < 65536)  { W = W12; Wt = Wt12; kshift = 8; NC = 256; }
    else if ((id -= 65536) < 65536)  { W = W21; Wt = Wt21; kshift = 8; NC = 256; }
    else if ((id -= 65536) < 16384)  { W = W22; Wt = Wt22; kshift = 8; NC = 64;  }
    else return;
    int K = 1 << kshift;
    int n = id >> kshift;
    int k = id & (K - 1);
    Wt[id] = f2b(W[(long long)k * NC + n]);
}

// ================= gather aggregation (bf16, fp32 accum) =================
// Lane owns 16B (8 bf16); 2 edge-groups of 32 lanes; unroll-4 in flight.
__global__ __launch_bounds__(256) void agg256_bf16(
    const u16x8* __restrict__ x, const int* __restrict__ row_ptr,
    const int* __restrict__ csr_src, const float* __restrict__ eps_ptr,
    u16x8* __restrict__ out, int Nn)
{
    int n = blockIdx.x * 4 + (threadIdx.x >> 6);
    if (n >= Nn) return;
    int lane = threadIdx.x & 63;
    int grp = lane >> 5;       // 0/1
    int sl  = lane & 31;       // chunk index
    size_t off = (size_t)n * 32 + sl;
    float acc[8];
    if (grp == 0) {
        float e1 = 1.0f + (eps_ptr ? *eps_ptr : 0.0f);
        u16x8 xv = x[off];
#pragma unroll
        for (int i = 0; i < 8; ++i) acc[i] = e1 * b2f(xv[i]);
    } else {
#pragma unroll
        for (int i = 0; i < 8; ++i) acc[i] = 0.0f;
    }
    int end = row_ptr[n + 1];
    int j = row_ptr[n] + grp;
    for (; j + 6 < end; j += 8) {          // 4 edges/group in flight
        int s0 = csr_src[j],     s1 = csr_src[j + 2];
        int s2 = csr_src[j + 4], s3 = csr_src[j + 6];
        u16x8 v0 = x[(size_t)s0 * 32 + sl];
        u16x8 v1 = x[(size_t)s1 * 32 + sl];
        u16x8 v2 = x[(size_t)s2 * 32 + sl];
        u16x8 v3 = x[(size_t)s3 * 32 + sl];
#pragma unroll
        for (int i = 0; i < 8; ++i)
            acc[i] += (b2f(v0[i]) + b2f(v1[i])) + (b2f(v2[i]) + b2f(v3[i]));
    }
    for (; j < end; j += 2) {
        u16x8 v = x[(size_t)csr_src[j] * 32 + sl];
#pragma unroll
        for (int i = 0; i < 8; ++i) acc[i] += b2f(v[i]);
    }
#pragma unroll
    for (int i = 0; i < 8; ++i) acc[i] += __shfl_xor(acc[i], 32, 64);
    if (grp == 0) {
        u16x8 o;
#pragma unroll
        for (int i = 0; i < 8; ++i) o[i] = f2b(acc[i]);
        out[off] = o;
    }
}

__global__ __launch_bounds__(256) void agg128_bf16(
    const u16x8* __restrict__ x, const int* __restrict__ row_ptr,
    const int* __restrict__ csr_src, const float* __restrict__ eps_ptr,
    u16x8* __restrict__ out, int Nn)
{
    int n = blockIdx.x * 4 + (threadIdx.x >> 6);
    if (n >= Nn) return;
    int lane = threadIdx.x & 63;
    int grp = lane >> 4;       // 0..3
    int sl  = lane & 15;
    size_t off = (size_t)n * 16 + sl;
    float acc[8];
    if (grp == 0) {
        float e1 = 1.0f + (eps_ptr ? *eps_ptr : 0.0f);
        u16x8 xv = x[off];
#pragma unroll
        for (int i = 0; i < 8; ++i) acc[i] = e1 * b2f(xv[i]);
    } else {
#pragma unroll
        for (int i = 0; i < 8; ++i) acc[i] = 0.0f;
    }
    int end = row_ptr[n + 1];
    int j = row_ptr[n] + grp;
    for (; j + 4 < end; j += 8) {
        int s0 = csr_src[j], s1 = csr_src[j + 4];
        u16x8 v0 = x[(size_t)s0 * 16 + sl];
        u16x8 v1 = x[(size_t)s1 * 16 + sl];
#pragma unroll
        for (int i = 0; i < 8; ++i) acc[i] += b2f(v0[i]) + b2f(v1[i]);
    }
    if (j < end) {
        u16x8 v = x[(size_t)csr_src[j] * 16 + sl];
#pragma unroll
        for (int i = 0; i < 8; ++i) acc[i] += b2f(v[i]);
    }
#pragma unroll
    for (int i = 0; i < 8; ++i) {
        acc[i] += __shfl_xor(acc[i], 16, 64);
        acc[i] += __shfl_xor(acc[i], 32, 64);
    }
    if (grp == 0) {
        u16x8 o;
#pragma unroll
        for (int i = 0; i < 8; ++i) o[i] = f2b(acc[i]);
        out[off] = o;
    }
}

// ================= persistent weight-stationary GEMM (NC-split) =================
// C[M, n0:n0+NCB] = A[M,K](bf16) @ Wt[n0:n0+NCB, K]^T  (+bias; FUSE as before)
// 512 thr / 8 waves. Block stages its NCB-col W slice into LDS ONCE
// (64KB @ NCB=128,K=256 -> 80KB total -> 2 blocks/CU), then grid-strides
// (gridDim.x) over 32-row A-tiles with reg-staged A prefetch (T14).
// Swapped-operand MFMA: D=mfma(W,A): W-row(out col) -> (l>>4)*4+j, node -> l&15.
// LDS tiles [rows][K] bf16; logical 16B granule g of row r at physical g^(r&7).
using bf16x8 = __attribute__((ext_vector_type(8))) short;
using f32x4  = __attribute__((ext_vector_type(4))) float;

__device__ inline void gload_lds16(const void* g, void* l) {
    __builtin_amdgcn_global_load_lds(
        (const __attribute__((address_space(1))) u32*)g,
        (__attribute__((address_space(3))) u32*)l, 16, 0, 0);
}

template <int K, int NC, int NCB, int FUSE, bool OF32>
__global__ __launch_bounds__(512) void gemm_ws(
    const u16* __restrict__ A, const u16* __restrict__ Wt,
    const float* __restrict__ bias,
    const float* __restrict__ bn_g, const float* __restrict__ bn_b,
    const float* __restrict__ bn_m, const float* __restrict__ bn_v,
    void* __restrict__ Cout, int M, int ntiles)
{
    constexpr int GPR  = K / 8;                    // 16B granules per row
    constexpr int AREG = (32 * GPR) / 512;         // granules per thread (1 or 2)
    constexpr int MF   = (NCB == 64) ? 1 : 2;
    constexpr int NF   = (NCB == 64) ? 1 : (NCB / 8) / 16;
    __shared__ __align__(16) u16 Wl[NCB * K];
    __shared__ __align__(16) u16 Al[32 * K];

    const int tid  = threadIdx.x;
    const int wv   = tid >> 6;
    const int lane = tid & 63;
    const int l15  = lane & 15, l4 = lane >> 4;
    const int n0   = blockIdx.y * NCB;
    const int rbase = (NCB == 64) ? (wv >> 2) * 16 : 0;
    const int cloc  = (NCB == 64) ? (wv & 3) * 16 : wv * (NCB / 8);

    // ---- stage this block's W slice into LDS (once) ----
    constexpr int WIW = (NCB * GPR / 64) / 8;      // instrs per wave
#pragma unroll
    for (int i = 0; i < WIW; ++i) {
        int inst = wv * WIW + i;
        int gi = inst * 64 + lane;
        int row = gi / GPR;                         // local W row
        int g = gi % GPR;
        gload_lds16(Wt + (size_t)(n0 + row) * K + (g ^ (row & 7)) * 8,
                    Wl + inst * 512);
    }

    // ---- per-thread A-tile register prefetch ----
    u32x4 areg[AREG];
    auto loadA = [&](int t) {
#pragma unroll
        for (int i = 0; i < AREG; ++i) {
            int gi = i * 512 + tid;
            int row = gi / GPR;
            int g = gi % GPR;
            int grow = t * 32 + row; if (grow >= M) grow = M - 1;
            areg[i] = *reinterpret_cast<const u32x4*>(
                A + (size_t)grow * K + (g ^ (row & 7)) * 8);
        }
    };

    loadA(blockIdx.x);
    __syncthreads();                       // W staged + first A regs ready

    for (int t = blockIdx.x; t < ntiles; t += gridDim.x) {
        // write A(t) regs -> LDS
#pragma unroll
        for (int i = 0; i < AREG; ++i) {
            int gi = i * 512 + tid;
            *reinterpret_cast<u32x4*>(Al + gi * 8) = areg[i];
        }
        __syncthreads();                   // A visible

        int tn = t + gridDim.x;
        if (tn < ntiles) loadA(tn);        // in flight under compute

        f32x4 acc[MF][NF] = {};
#pragma unroll
        for (int s = 0; s < K / 32; ++s) {
            int g = s * 4 + l4;
            bf16x8 wf[NF], af[MF];
#pragma unroll
            for (int n = 0; n < NF; ++n) {
                int wrow = cloc + n * 16 + l15;
                wf[n] = *(const bf16x8*)(Wl + wrow * K + ((g ^ (wrow & 7)) * 8));
            }
#pragma unroll
            for (int m = 0; m < MF; ++m) {
                int arow = rbase + m * 16 + l15;
                af[m] = *(const bf16x8*)(Al + arow * K + ((g ^ (arow & 7)) * 8));
            }
#pragma unroll
            for (int m = 0; m < MF; ++m)
#pragma unroll
                for (int n = 0; n < NF; ++n)
                    acc[m][n] = __builtin_amdgcn_mfma_f32_16x16x32_bf16(
                        wf[n], af[m], acc[m][n], 0, 0, 0);
        }

        // ---- fused epilogue, store tile t ----
#pragma unroll
        for (int m = 0; m < MF; ++m) {
            int grow = t * 32 + rbase + m * 16 + l15;
            if (grow < M) {
#pragma unroll
                for (int n = 0; n < NF; ++n) {
                    int col = n0 + cloc + n * 16 + l4 * 4;
                    float4 bv = ld4(bias + col);
                    float v0 = acc[m][n][0] + bv.x;
                    float v1 = acc[m][n][1] + bv.y;
                    float v2 = acc[m][n][2] + bv.z;
                    float v3 = acc[m][n][3] + bv.w;
                    if (FUSE == 0) {
                        v0 = fmaxf(v0, 0.f); v1 = fmaxf(v1, 0.f);
                        v2 = fmaxf(v2, 0.f); v3 = fmaxf(v3, 0.f);
                    } else if (FUSE == 1) {
                        float4 g4 = ld4(bn_g + col), be = ld4(bn_b + col);
                        float4 mm = ld4(bn_m + col), vv = ld4(bn_v + col);
                        float s0 = g4.x * rsqrtf(vv.x + 1e-5f);
                        float s1 = g4.y * rsqrtf(vv.y + 1e-5f);
                        float s2 = g4.z * rsqrtf(vv.z + 1e-5f);
                        float s3 = g4.w * rsqrtf(vv.w + 1e-5f);
                        v0 = fmaf(v0, s0, be.x - mm.x * s0);
                        v1 = fmaf(v1, s1, be.y - mm.y * s1);
                        v2 = fmaf(v2, s2, be.z - mm.z * s2);
                        v3 = fmaf(v3, s3, be.w - mm.w * s3);
                        v0 = v0 >= 0.f ? v0 : 0.01f * v0;
                        v1 = v1 >= 0.f ? v1 : 0.01f * v1;
                        v2 = v2 >= 0.f ? v2 : 0.01f * v2;
                        v3 = v3 >= 0.f ? v3 : 0.01f * v3;
                    }
                    if (OF32) {
                        float4 o = make_float4(v0, v1, v2, v3);
                        *reinterpret_cast<float4*>(
                            (float*)Cout + (size_t)grow * NC + col) = o;
                    } else {
                        u32 p0 = (u32)f2b(v0) | ((u32)f2b(v1) << 16);
                        u32 p1 = (u32)f2b(v2) | ((u32)f2b(v3) << 16);
                        *reinterpret_cast<uint2*>(
                            (u16*)Cout + (size_t)grow * NC + col) = make_uint2(p0, p1);
                    }
                }
            }
        }
        __syncthreads();   // all waves done reading Al before next overwrite
    }
}

extern "C" void kernel_launch(void* const* d_in, const int* in_sizes, int n_in,
                              void* d_out, int out_size, void* d_ws, size_t ws_size,
                              hipStream_t stream)
{
    const float* x    = (const float*)d_in[0];
    const int*   ei   = (const int*)d_in[1];     // int32: [src(E), dst(E)]
    const float* eps0 = (const float*)d_in[2];
    const float* W01  = (const float*)d_in[3];
    const float* b01  = (const float*)d_in[4];
    const float* W02  = (const float*)d_in[5];
    const float* b02  = (const float*)d_in[6];
    const float* W11  = (const float*)d_in[7];
    const float* b11  = (const float*)d_in[8];
    const float* W12  = (const float*)d_in[9];
    const float* b12  = (const float*)d_in[10];
    const float* eps2 = (const float*)d_in[11];
    const float* W21  = (const float*)d_in[12];
    const float* b21  = (const float*)d_in[13];
    const float* W22  = (const float*)d_in[14];
    const float* b22  = (const float*)d_in[15];
    const float* bn_g = (const float*)d_in[16];
    const float* bn_b = (const float*)d_in[17];
    const float* bn_m = (const float*)d_in[18];
    const float* bn_v = (const float*)d_in[19];

    const int Nn = in_sizes[0] / IN_F;   // 50000
    const int E  = in_sizes[1] / 2;      // 600000

    // ---- workspace carve-up ----
    u16* P = (u16*)d_ws;                        // agg output
    u16* Q = P + (size_t)Nn * HID;              // layer output
    u16* R = Q + (size_t)Nn * HID;              // H intermediate
    u16* Xb = R + (size_t)Nn * HID;
    u16* Wt01 = Xb + (size_t)Nn * IN_F;
    u16* Wt02 = Wt01 + HID * IN_F;
    u16* Wt11 = Wt02 + HID * HID;
    u16* Wt12 = Wt11 + HID * HID;
    u16* Wt21 = Wt12 + HID * HID;
    u16* Wt22 = Wt21 + HID * HID;
    int* row_ptr = (int*)(Wt22 + OUT_F * HID);
    int* cursor  = row_ptr + (Nn + 1);
    int* deg     = cursor + Nn;
    int* blksum  = deg + Nn;
    int* csr_src = blksum + 1024;

    dim3 blk(256);
    const int nwave_blocks = cdiv_i(Nn, 4);
    const int nscan = cdiv_i(Nn, 1024);

    // ---- CSR build (by dst), two-level scan ----
    hipMemsetAsync(deg, 0, (size_t)Nn * sizeof(int), stream);
    deg_count_kernel<<<cdiv_i(E, 256), blk, 0, stream>>>(ei, deg, E);
    block_scan_kernel<<<nscan, 1024, 0, stream>>>(deg, row_ptr, blksum, Nn);
    scan_blksums_kernel<<<1, 1024, 0, stream>>>(blksum, nscan);
    add_offsets_kernel<<<cdiv_i(Nn + 1, 1024), 1024, 0, stream>>>(
        row_ptr, cursor, blksum, Nn, E);
    csr_fill_kernel<<<cdiv_i(E, 256), blk, 0, stream>>>(ei, cursor, csr_src, E);

    // ---- convert x and weights to bf16 ----
    xconv_kernel<<<cdiv_i((long long)Nn * IN_F / 4, 256), blk, 0, stream>>>(
        (const float4*)x, (ushort4*)Xb, (long long)Nn * IN_F / 4);
    wconv_all_kernel<<<cdiv_i(32768 + 4 * 65536 + 16384, 256), blk, 0, stream>>>(
        W01, W02, W11, W12, W21, W22, Wt01, Wt02, Wt11, Wt12, Wt21, Wt22);

    const int ntiles = cdiv_i(Nn, 32);          // 1563
    const dim3 blk512(512);

    // ================= layer 0 (in=128) =================
    agg128_bf16<<<nwave_blocks, blk, 0, stream>>>(
        (const u16x8*)Xb, row_ptr, csr_src, eps0, (u16x8*)P, Nn);
    gemm_ws<128, 256, 256, 0, false><<<dim3(512, 1), blk512, 0, stream>>>(  // 72KB
        P, Wt01, b01, nullptr, nullptr, nullptr, nullptr, R, Nn, ntiles);
    gemm_ws<256, 256, 128, 1, false><<<dim3(256, 2), blk512, 0, stream>>>(  // 80KB
        R, Wt02, b02, bn_g, bn_b, bn_m, bn_v, Q, Nn, ntiles);

    // ================= layer 1 =================
    agg256_bf16<<<nwave_blocks, blk, 0, stream>>>(
        (const u16x8*)Q, row_ptr, csr_src, nullptr, (u16x8*)P, Nn);
    gemm_ws<256, 256, 128, 0, false><<<dim3(256, 2), blk512, 0, stream>>>(
        P, Wt11, b11, nullptr, nullptr, nullptr, nullptr, R, Nn, ntiles);
    gemm_ws<256, 256, 128, 1, false><<<dim3(256, 2), blk512, 0, stream>>>(
        R, Wt12, b12, bn_g, bn_b, bn_m, bn_v, Q, Nn, ntiles);

    // ================= layer 2 (out=64) =================
    agg256_bf16<<<nwave_blocks, blk, 0, stream>>>(
        (const u16x8*)Q, row_ptr, csr_src, eps2, (u16x8*)P, Nn);
    gemm_ws<256, 256, 128, 0, false><<<dim3(256, 2), blk512, 0, stream>>>(
        P, Wt21, b21, nullptr, nullptr, nullptr, nullptr, R, Nn, ntiles);
    gemm_ws<256, 64, 64, 2, true><<<dim3(512, 1), blk512, 0, stream>>>(     // 48KB
        R, Wt22, b22, nullptr, nullptr, nullptr, nullptr, d_out, Nn, ntiles);
}